// Round 9
// baseline (384.906 us; speedup 1.0000x reference)
//
#include <hip/hip_runtime.h>
#include <hip/hip_bf16.h>
#include <hip/hip_fp16.h>
#include <hip/hip_cooperative_groups.h>

namespace cg = cooperative_groups;

// Problem constants: B=2, N=10000, M=320000, QD=KD=HD=256, NUM_HEADS=8, dh=32.
#define DHID 256
#define NHEAD 8
#define BATCH 2

typedef _Float16 h8 __attribute__((ext_vector_type(8)));
typedef float f4 __attribute__((ext_vector_type(4)));

// One cooperative kernel: prep -> gsync -> GEMM -> gsync -> edge -> gsync -> norm.
// 32 KB static LDS (As+Bs) -> 4-5 co-resident blocks/CU (occupancy-query sized).
__global__ __launch_bounds__(256, 4) void mega_kernel(
    const float* __restrict__ Xq, const float* __restrict__ Xk,
    const int* __restrict__ mask,
    const float* __restrict__ Wq, const float* __restrict__ Wk,
    float* __restrict__ out,
    _Float16* __restrict__ Qh, _Float16* __restrict__ Kh,
    _Float16* __restrict__ Wtq, _Float16* __restrict__ Wtk,
    float* __restrict__ seg, int M, int N)
{
    cg::grid_group grid = cg::this_grid();
    __shared__ _Float16 As[32 * 256];   // 16 KB
    __shared__ _Float16 Bs[32 * 256];   // 16 KB

    const int t    = threadIdx.x;
    const int lane = t & 63;
    const int wave = t >> 6;
    const int nblk = gridDim.x;
    const int Mrows = BATCH * N;        // 20000
    const int segN  = BATCH * N * NHEAD;

    // ---------------- Phase 0: zero seg + transpose W -> fp16 Wt ----------
    for (int i = blockIdx.x * 256 + t; i < segN; i += nblk * 256) seg[i] = 0.f;
    if (blockIdx.x < 128) {
        const int tt = blockIdx.x;
        const float* W = (tt & 64) ? Wk : Wq;
        _Float16* Wt   = (tt & 64) ? Wtk : Wtq;
        const int tile = tt & 63;
        const int n0 = (tile & 7) * 32;
        const int k0 = (tile >> 3) * 32;
        float* tf = (float*)As;         // 32x33 floats = 4224 B, aliases As
        const int tx = t & 31, ty = t >> 5;
#pragma unroll
        for (int j = 0; j < 32; j += 8)
            tf[(ty + j) * 33 + tx] = W[(size_t)(k0 + ty + j) * DHID + n0 + tx];
        __syncthreads();
#pragma unroll
        for (int j = 0; j < 32; j += 8)
            Wt[(size_t)(n0 + ty + j) * DHID + k0 + tx] = (_Float16)tf[tx * 33 + ty + j];
    }
    grid.sync();

    // ---------------- Phase 1: GEMM (32-row strips, grid-stride) ----------
    // Wave w owns out-tile (row-half w&1, col-half w>>1) of each 32x32 chunk.
    {
        const int SP = Mrows / 32;          // 625 strips per matrix
        const int m = lane & 15, quad = lane >> 4;
        for (int s = blockIdx.x; s < 2 * SP; s += nblk) {
            const bool isK = (s >= SP);
            const float* X     = isK ? Xk : Xq;
            const _Float16* Wt = isK ? Wtk : Wtq;
            _Float16* C        = isK ? Kh : Qh;
            const int rowBase  = (isK ? s - SP : s) * 32;

            // stage A: 32 rows x 256 k, fp32 -> fp16, swizzled 16B chunks
#pragma unroll
            for (int i = 0; i < 4; ++i) {
                int idx = t + i * 256;          // 0..1023
                int row = idx >> 5, c = idx & 31;
                const float* p = X + (size_t)(rowBase + row) * DHID + c * 8;
                f4 v0 = *(const f4*)p, v1 = *(const f4*)(p + 4);
                h8 hv;
                hv[0]=(_Float16)v0[0]; hv[1]=(_Float16)v0[1]; hv[2]=(_Float16)v0[2]; hv[3]=(_Float16)v0[3];
                hv[4]=(_Float16)v1[0]; hv[5]=(_Float16)v1[1]; hv[6]=(_Float16)v1[2]; hv[7]=(_Float16)v1[3];
                *(h8*)&As[row * 256 + (c ^ (row & 7)) * 8] = hv;
            }
            __syncthreads();

            const int ar = (wave & 1) * 16 + m;
            h8 af[8];
#pragma unroll
            for (int kc = 0; kc < 8; ++kc)
                af[kc] = *(const h8*)&As[ar * 256 + (((kc * 4 + quad) ^ (ar & 7)) * 8)];

            const int ch = (wave >> 1) * 16;
            const int bn = ch + m;
            for (int cc = 0; cc < 8; ++cc) {    // 8 col-chunks of 32
#pragma unroll
                for (int i = 0; i < 4; ++i) {
                    int idx = t + i * 256;
                    int n = idx >> 5, c = idx & 31;
                    h8 hv = *(const h8*)(Wt + (size_t)(cc * 32 + n) * DHID + c * 8);
                    *(h8*)&Bs[n * 256 + (c ^ (n & 7)) * 8] = hv;
                }
                __syncthreads();

                f4 acc = {0, 0, 0, 0};
#pragma unroll
                for (int kc = 0; kc < 8; ++kc) {
                    h8 bf = *(const h8*)&Bs[bn * 256 + (((kc * 4 + quad) ^ (bn & 7)) * 8)];
                    acc = __builtin_amdgcn_mfma_f32_16x16x32_f16(af[kc], bf, acc, 0, 0, 0);
                }
                const int col = cc * 32 + ch + m;
#pragma unroll
                for (int r = 0; r < 4; ++r) {
                    int grow = rowBase + (wave & 1) * 16 + quad * 4 + r;
                    C[(size_t)grow * DHID + col] = (_Float16)acc[r];
                }
                __syncthreads();
            }
        }
    }
    grid.sync();

    // ---------------- Phase 2: edge (8 edges/wave, r5 winner) -------------
    // Global max subtraction cancels in e/seg -> skipped.
    {
        const int nIt = (M + 31) / 32;      // 32 edges per block-iter
        const int g = lane >> 3, h = lane & 7;
        for (int it = blockIdx.x; it < 2 * nIt; it += nblk) {
            const int b  = (it >= nIt);
            const long e0 = (long)(b ? it - nIt : it) * 32 + wave * 8;
            if (e0 >= M) continue;

            int idxv = 0;
            {
                long le = e0 + (lane & 7);
                if (le >= M) le = M - 1;
                if (lane < 8)       idxv = mask[le];
                else if (lane < 16) idxv = mask[M + le];
            }
            const int src = __shfl(idxv, g);
            const int dst = __shfl(idxv, 8 + g);

            const h8* qp = (const h8*)(Qh + ((size_t)b * N + src) * DHID + h * 32);
            const h8* kp = (const h8*)(Kh + ((size_t)b * N + dst) * DHID + h * 32);
            h8 a0 = qp[0], a1 = qp[1], a2 = qp[2], a3 = qp[3];
            h8 c0 = kp[0], c1 = kp[1], c2 = kp[2], c3 = kp[3];

            float s0 = 0.f, s1 = 0.f, s2 = 0.f, s3 = 0.f;
#pragma unroll
            for (int u = 0; u < 8; ++u) {
                s0 += (float)a0[u] * (float)c0[u];
                s1 += (float)a1[u] * (float)c1[u];
                s2 += (float)a2[u] * (float)c2[u];
                s3 += (float)a3[u] * (float)c3[u];
            }
            float s = (s0 + s1) + (s2 + s3);

            const long e = e0 + g;
            if (e < M) {
                float ev = expf(s * 0.0625f);   // 1/sqrt(256)
                out[((size_t)b * M + e) * NHEAD + h] = ev;
                atomicAdd(seg + ((size_t)b * N + src) * NHEAD + h, ev);
            }
        }
    }
    grid.sync();

    // ---------------- Phase 3: normalize ----------------------------------
    {
        const int BM = BATCH * M;
        for (int idx = blockIdx.x * 256 + t; idx < BM; idx += nblk * 256) {
            int b = idx / M;
            int e = idx - b * M;
            int src = mask[e];
            const float4* s4 = (const float4*)(seg + ((size_t)b * N + src) * NHEAD);
            float4 s0 = s4[0], s1 = s4[1];
            float4* o4 = (float4*)(out + (size_t)idx * NHEAD);
            float4 o0 = o4[0], o1 = o4[1];
            o0.x /= (s0.x + 1e-16f); o0.y /= (s0.y + 1e-16f);
            o0.z /= (s0.z + 1e-16f); o0.w /= (s0.w + 1e-16f);
            o1.x /= (s1.x + 1e-16f); o1.y /= (s1.y + 1e-16f);
            o1.z /= (s1.z + 1e-16f); o1.w /= (s1.w + 1e-16f);
            o4[0] = o0; o4[1] = o1;
        }
    }
}

extern "C" void kernel_launch(void* const* d_in, const int* in_sizes, int n_in,
                              void* d_out, int out_size, void* d_ws, size_t ws_size,
                              hipStream_t stream) {
    const float* x_q  = (const float*)d_in[0];
    const float* x_k  = (const float*)d_in[1];
    const int*   mask = (const int*)d_in[2];
    const float* w_q  = (const float*)d_in[3];
    const float* w_k  = (const float*)d_in[4];
    float* out = (float*)d_out;

    int M = in_sizes[2] / 2;                 // 320000
    int N = in_sizes[0] / (BATCH * DHID);    // 10000
    const int Mrows = BATCH * N;             // 20000

    _Float16* Qh  = (_Float16*)d_ws;
    _Float16* Kh  = Qh  + (size_t)Mrows * DHID;
    _Float16* Wtq = Kh  + (size_t)Mrows * DHID;
    _Float16* Wtk = Wtq + (size_t)DHID * DHID;
    float*    seg = (float*)(Wtk + (size_t)DHID * DHID);

    // co-resident grid size: blocks/CU from occupancy query x 256 CUs
    int bpcu = 0;
    hipOccupancyMaxActiveBlocksPerMultiprocessor(&bpcu, mega_kernel, 256, 0);
    if (bpcu < 1) bpcu = 2;
    int ncu = 0;
    hipDeviceGetAttribute(&ncu, hipDeviceAttributeMultiprocessorCount, 0);
    if (ncu < 1) ncu = 256;
    unsigned grid = (unsigned)(bpcu * ncu);

    void* args[] = { (void*)&x_q, (void*)&x_k, (void*)&mask, (void*)&w_q, (void*)&w_k,
                     (void*)&out, (void*)&Qh, (void*)&Kh, (void*)&Wtq, (void*)&Wtk,
                     (void*)&seg, (void*)&M, (void*)&N };
    hipLaunchCooperativeKernel((const void*)mega_kernel, dim3(grid), dim3(256),
                               args, 0, stream);
}

// Round 11
// 181.619 us; speedup vs baseline: 2.1193x; 2.1193x over previous
//
#include <hip/hip_runtime.h>
#include <hip/hip_bf16.h>
#include <hip/hip_fp16.h>

// Problem constants: B=2, N=10000, M=320000, QD=KD=HD=256, NUM_HEADS=8, dh=32.
#define DHID 256
#define NHEAD 8
#define BATCH 2

typedef _Float16 h8 __attribute__((ext_vector_type(8)));
typedef float f4 __attribute__((ext_vector_type(4)));

// ---------------- P0: W transpose->fp16 (z=0,1) + zero seg (z=2) ----------
__global__ __launch_bounds__(256) void prep_kernel(
    const float* __restrict__ Wq, const float* __restrict__ Wk,
    _Float16* __restrict__ Wtq, _Float16* __restrict__ Wtk,
    float* __restrict__ seg, int segN)
{
    if (blockIdx.z == 2) {
        int idx = (blockIdx.x * 8 + blockIdx.y) * 256 + threadIdx.y * 32 + threadIdx.x;
        for (int i = idx; i < segN; i += 64 * 256) seg[i] = 0.f;
        return;
    }
    const float* W = blockIdx.z ? Wk : Wq;
    _Float16* Wt   = blockIdx.z ? Wtk : Wtq;
    __shared__ float tile[32][33];
    const int tx = threadIdx.x;   // 0..31
    const int ty = threadIdx.y;   // 0..7
    const int n0 = blockIdx.x * 32;
    const int k0 = blockIdx.y * 32;
#pragma unroll
    for (int j = 0; j < 32; j += 8)
        tile[ty + j][tx] = W[(size_t)(k0 + ty + j) * DHID + n0 + tx];
    __syncthreads();
#pragma unroll
    for (int j = 0; j < 32; j += 8)
        Wt[(size_t)(n0 + ty + j) * DHID + k0 + tx] = (_Float16)tile[tx][ty + j];
}

// ---------------- MFMA GEMM, A-stationary (round-5 winner, unchanged) -----
__global__ __launch_bounds__(256, 2) void gemm_mfma(
    const float* __restrict__ Xq, const float* __restrict__ Xk,
    const _Float16* __restrict__ Wtq, const _Float16* __restrict__ Wtk,
    _Float16* __restrict__ Qh, _Float16* __restrict__ Kh, int Mrows)
{
    const float* X       = blockIdx.z ? Xk : Xq;
    const _Float16* Wt   = blockIdx.z ? Wtk : Wtq;
    _Float16* C          = blockIdx.z ? Kh : Qh;

    __shared__ _Float16 As[64 * 256];   // 32 KB, [row][k] swizzled
    __shared__ _Float16 Bs[64 * 256];   // 32 KB, [n][k]   swizzled

    const int t    = threadIdx.x;
    const int lane = t & 63;
    const int wave = t >> 6;
    const int rowBase = blockIdx.x * 64;

#pragma unroll
    for (int i = 0; i < 8; ++i) {
        int idx = t + i * 256;          // 0..2047
        int row = idx >> 5;
        int c   = idx & 31;
        int grow = rowBase + row;
        f4 v0 = {0,0,0,0}, v1 = {0,0,0,0};
        if (grow < Mrows) {
            const float* p = X + (size_t)grow * DHID + c * 8;
            v0 = *(const f4*)p;
            v1 = *(const f4*)(p + 4);
        }
        h8 hv;
        hv[0]=(_Float16)v0[0]; hv[1]=(_Float16)v0[1]; hv[2]=(_Float16)v0[2]; hv[3]=(_Float16)v0[3];
        hv[4]=(_Float16)v1[0]; hv[5]=(_Float16)v1[1]; hv[6]=(_Float16)v1[2]; hv[7]=(_Float16)v1[3];
        int sc = c ^ (row & 7);
        *(h8*)&As[row * 256 + sc * 8] = hv;
    }

    const int ar   = wave * 16 + (lane & 15);
    const int quad = lane >> 4;

    for (int ct64 = 0; ct64 < 4; ++ct64) {
#pragma unroll
        for (int i = 0; i < 8; ++i) {
            int idx = t + i * 256;
            int n = idx >> 5;
            int c = idx & 31;
            h8 hv = *(const h8*)(Wt + (size_t)(ct64 * 64 + n) * DHID + c * 8);
            int sc = c ^ (n & 7);
            *(h8*)&Bs[n * 256 + sc * 8] = hv;
        }
        __syncthreads();

        f4 acc[4] = {{0,0,0,0},{0,0,0,0},{0,0,0,0},{0,0,0,0}};
#pragma unroll
        for (int kc = 0; kc < 8; ++kc) {            // K chunk of 32
            int ac = (kc * 4 + quad) ^ (ar & 7);
            h8 afrag = *(const h8*)&As[ar * 256 + ac * 8];
#pragma unroll
            for (int ct = 0; ct < 4; ++ct) {
                int bn = ct * 16 + (lane & 15);
                int bc = (kc * 4 + quad) ^ (bn & 7);
                h8 bfrag = *(const h8*)&Bs[bn * 256 + bc * 8];
                acc[ct] = __builtin_amdgcn_mfma_f32_16x16x32_f16(afrag, bfrag, acc[ct], 0, 0, 0);
            }
        }

#pragma unroll
        for (int ct = 0; ct < 4; ++ct) {
#pragma unroll
            for (int r = 0; r < 4; ++r) {
                int grow = rowBase + wave * 16 + quad * 4 + r;
                if (grow < Mrows)
                    C[(size_t)grow * DHID + ct64 * 64 + ct * 16 + (lane & 15)] = (_Float16)acc[ct][r];
            }
        }
        __syncthreads();
    }
}

// ---------------- Edge kernel v2: contiguous-row gathers ------------------
// lane = (edge-pair half, 16B chunk c). 32 consecutive lanes read one row
// CONTIGUOUSLY: each gather instr touches 8 cache lines (2 rows x 4) vs 32
// in the (edge,head) layout -> 4x fewer TA line-transactions, which the
// round-9 model says is the hidden ~50%-busy pipe. Head h = chunk c>>2;
// reduction = 2 shfl_xor within 4-lane quads.
// Global max subtraction cancels in e/seg -> skipped.
__global__ __launch_bounds__(256, 6) void edge_kernel(
    const _Float16* __restrict__ Qh, const _Float16* __restrict__ Kh,
    const int* __restrict__ mask, float* __restrict__ out,
    float* __restrict__ seg, int M, int N)
{
    const int lane = threadIdx.x & 63;
    const int wave = threadIdx.x >> 6;
    const int c    = lane & 31;     // 16B chunk within row (c*8 halves)
    const int half = lane >> 5;     // which edge of the pair
    const int h    = c >> 2;        // head of this chunk
    const long e0 = ((long)blockIdx.x * 4 + wave) * 8;
    const int b = blockIdx.y;
    if (e0 >= M) return;

    // lanes 0..7: src of edges e0..e0+7; lanes 8..15: dst
    int idxv = 0;
    {
        long le = e0 + (lane & 7);
        if (le >= M) le = M - 1;
        if (lane < 8)       idxv = mask[le];
        else if (lane < 16) idxv = mask[M + le];
    }

    const _Float16* Qb = Qh + (size_t)b * N * DHID;
    const _Float16* Kb = Kh + (size_t)b * N * DHID;

    int sidx[4], didx[4];
#pragma unroll
    for (int p = 0; p < 4; ++p) {
        sidx[p] = __shfl(idxv, p * 2 + half);
        didx[p] = __shfl(idxv, 8 + p * 2 + half);
    }

    // ---- load phase: 8 instrs, each 2 full rows contiguous (512B x 2) ----
    h8 qv[4], kv[4];
#pragma unroll
    for (int p = 0; p < 4; ++p) {
        qv[p] = *(const h8*)(Qb + (size_t)sidx[p] * DHID + c * 8);
        kv[p] = *(const h8*)(Kb + (size_t)didx[p] * DHID + c * 8);
    }

    // ---- compute + emit ----
#pragma unroll
    for (int p = 0; p < 4; ++p) {
        float s = 0.f;
#pragma unroll
        for (int u = 0; u < 8; ++u)
            s += (float)qv[p][u] * (float)kv[p][u];
        s += __shfl_xor(s, 1);
        s += __shfl_xor(s, 2);          // quad c&~3..c|3 now holds head sum
        float ev = expf(s * 0.0625f);   // 1/sqrt(256) = 1/16
        const long e = e0 + p * 2 + half;
        if ((c & 3) == 0 && e < M) {
            __builtin_nontemporal_store(ev, &out[((size_t)b * M + e) * NHEAD + h]);
            atomicAdd(seg + ((size_t)b * N + sidx[p]) * NHEAD + h, ev);
        }
    }
}

// ---------------- Normalize: out = e / (seg[src] + 1e-16) -----------------
__global__ __launch_bounds__(256) void norm_kernel(
    const int* __restrict__ mask, const float* __restrict__ seg,
    float* __restrict__ out, int M, int N, int BM)
{
    int idx = blockIdx.x * 256 + threadIdx.x;   // idx = b*M + e
    if (idx >= BM) return;
    int b = idx / M;
    int e = idx - b * M;
    int src = mask[e];
    const f4* s4 = (const f4*)(seg + ((size_t)b * N + src) * NHEAD);
    f4 s0 = s4[0], s1 = s4[1];
    f4* o4 = (f4*)(out + (size_t)idx * NHEAD);
    f4 o0 = o4[0], o1 = o4[1];
    o0[0] *= __builtin_amdgcn_rcpf(s0[0] + 1e-16f);
    o0[1] *= __builtin_amdgcn_rcpf(s0[1] + 1e-16f);
    o0[2] *= __builtin_amdgcn_rcpf(s0[2] + 1e-16f);
    o0[3] *= __builtin_amdgcn_rcpf(s0[3] + 1e-16f);
    o1[0] *= __builtin_amdgcn_rcpf(s1[0] + 1e-16f);
    o1[1] *= __builtin_amdgcn_rcpf(s1[1] + 1e-16f);
    o1[2] *= __builtin_amdgcn_rcpf(s1[2] + 1e-16f);
    o1[3] *= __builtin_amdgcn_rcpf(s1[3] + 1e-16f);
    __builtin_nontemporal_store(o0, &o4[0]);
    __builtin_nontemporal_store(o1, &o4[1]);
}

extern "C" void kernel_launch(void* const* d_in, const int* in_sizes, int n_in,
                              void* d_out, int out_size, void* d_ws, size_t ws_size,
                              hipStream_t stream) {
    const float* x_q  = (const float*)d_in[0];
    const float* x_k  = (const float*)d_in[1];
    const int*   mask = (const int*)d_in[2];
    const float* w_q  = (const float*)d_in[3];
    const float* w_k  = (const float*)d_in[4];
    float* out = (float*)d_out;

    const int M = in_sizes[2] / 2;                 // 320000
    const int N = in_sizes[0] / (BATCH * DHID);    // 10000
    const int Mrows = BATCH * N;                   // 20000

    _Float16* Qh  = (_Float16*)d_ws;
    _Float16* Kh  = Qh  + (size_t)Mrows * DHID;
    _Float16* Wtq = Kh  + (size_t)Mrows * DHID;
    _Float16* Wtk = Wtq + (size_t)DHID * DHID;
    float*    seg = (float*)(Wtk + (size_t)DHID * DHID);

    // P0: transpose W to fp16 + zero seg (one launch)
    prep_kernel<<<dim3(DHID / 32, DHID / 32, 3), dim3(32, 8), 0, stream>>>(
        w_q, w_k, Wtq, Wtk, seg, BATCH * N * NHEAD);

    dim3 ggrid((Mrows + 63) / 64, 1, 2);
    gemm_mfma<<<ggrid, 256, 0, stream>>>(x_q, x_k, Wtq, Wtk, Qh, Kh, Mrows);

    // edge: 8 edges per wave, 4 waves per block
    long waves = (M + 7) / 8;
    dim3 egrid((unsigned)((waves + 3) / 4), BATCH);
    edge_kernel<<<egrid, 256, 0, stream>>>(Qh, Kh, mask, out, seg, M, N);

    const int BM = BATCH * M;
    norm_kernel<<<(BM + 255) / 256, 256, 0, stream>>>(mask, seg, out, M, N, BM);
}